// Round 4
// baseline (88.862 us; speedup 1.0000x reference)
//
#include <hip/hip_runtime.h>
#include <math.h>

// out[0] = (1 - mean(Y)) + 5e-5 / sqrt(min_d2), min over 64 batches x all
// unordered pairs of 1024 2-D points (x[b,20k], x[b,20k+1]).
//
// Bit-exactness: reference d2 = rn(rn(sq_n+sq_m) - 2*rn(rn(xx')+rn(yy'))).
// We store u=-2x, v=-2y (exact pow2 scalings). Then rn(u*x') = -2*rn(x*x'),
// rn(u*x' + v*y') = -2*rn(xx'+yy') (pow2 scaling commutes with rounding), so
// d2 = rn(t + e') is bit-identical. Verified absmax 0.0 in rounds 1/3 with
// this formulation's unscaled equivalent.
//
// Guard "d2 > 0" via uint-min: for d2>0, float bits order as uints;
// candidate = bits(d2)-1 maps +0.0 -> 0xFFFFFFFF and negatives -> >=0x7FFFFFFF,
// both above any positive-finite candidate and above INIT = bits(INF)-1.
// Final min = uint_as_float(global_min + 1).
//
// Enumeration: circulant m=(n+k)&1023, k=1..511 all n, k=512 only n<512.
// 4 consecutive points per thread; window of 4 float4 LDS entries slides by
// 1 per k. LDS layout: pts4[(j&3)*386 + (j>>2)], rows extended by 130
// duplicated entries so j up to 1539 needs no wrap -> all window loads are
// base + immediate offset.

#define NPTS    1024
#define XCOLS   20480
#define PSTRIDE 20
#define BPB     16              // blocks per batch
#define KRANGE  32              // 512 / BPB k-shifts per block
#define NBLOCKS (64 * BPB)      // 1024
#define ROWLEN  386             // 256 + 130 duplicated tail
#define ACC_INIT 0x7F7FFFFFu    // bits(+INF) - 1

__device__ __forceinline__ int widx(int j) {
    return (j & 3) * ROWLEN + (j >> 2);
}

__global__ __launch_bounds__(256) void spike_kernel(const float* __restrict__ x,
                                                    const float* __restrict__ Y,
                                                    float* __restrict__ out,
                                                    unsigned* __restrict__ ws) {
    // ws[0]: global min bits (memset 0xFF), ws[1]: arrival counter (0xFF...),
    // ws[2]: Y-sum as float bits (written by block 0)
    __shared__ float4 pts4[4 * ROWLEN];
    __shared__ unsigned wm[4];
    __shared__ int is_last;

    const int b   = blockIdx.x >> 4;        // batch
    const int q   = blockIdx.x & (BPB - 1); // k-slice
    const int tid = threadIdx.x;

    // Block 0: issue Y loads early (latency hidden under staging+compute)
    float yv = 0.0f;
    if (blockIdx.x == 0 && tid < 64) yv = Y[tid];

    // ---- stage batch points into LDS as (u=-2x, v=-2y, sq, 0) ----
    const float* xb = x + (size_t)b * XCOLS;
    #pragma unroll
    for (int i0 = 0; i0 < NPTS; i0 += 256) {
        const int i = i0 + tid;
        float2 p = *reinterpret_cast<const float2*>(xb + i * PSTRIDE);
        float sq = __fadd_rn(__fmul_rn(p.x, p.x), __fmul_rn(p.y, p.y));
        float4 v = make_float4(__fmul_rn(-2.0f, p.x), __fmul_rn(-2.0f, p.y), sq, 0.0f);
        const int g = i & 3, r = i >> 2;
        pts4[g * ROWLEN + r] = v;
        if (r < 130) pts4[g * ROWLEN + 256 + r] = v;   // wrap duplicate
    }
    __syncthreads();

    // Block 0: reduce+publish Y sum while others compute
    if (blockIdx.x == 0 && tid < 64) {
        float ys = yv;
        #pragma unroll
        for (int off = 32; off >= 1; off >>= 1)
            ys += __shfl_xor(ys, off, 64);
        if (tid == 0) ((float*)ws)[2] = ys;
    }

    // ---- own 4 points (reconstruct raw: x = -0.5*u exactly) ----
    const int n0 = tid << 2;
    float xo0, yo0, qo0, xo1, yo1, qo1, xo2, yo2, qo2, xo3, yo3, qo3;
    {
        float4 t;
        t = pts4[0 * ROWLEN + tid]; xo0 = __fmul_rn(-0.5f, t.x); yo0 = __fmul_rn(-0.5f, t.y); qo0 = t.z;
        t = pts4[1 * ROWLEN + tid]; xo1 = __fmul_rn(-0.5f, t.x); yo1 = __fmul_rn(-0.5f, t.y); qo1 = t.z;
        t = pts4[2 * ROWLEN + tid]; xo2 = __fmul_rn(-0.5f, t.x); yo2 = __fmul_rn(-0.5f, t.y); qo2 = t.z;
        t = pts4[3 * ROWLEN + tid]; xo3 = __fmul_rn(-0.5f, t.x); yo3 = __fmul_rn(-0.5f, t.y); qo3 = t.z;
    }

    const int kstart = q * KRANGE + 1;
    const int base   = n0 + kstart;

    float4 w0 = pts4[widx(base)];
    float4 w1 = pts4[widx(base + 1)];
    float4 w2 = pts4[widx(base + 2)];
    float4 w3 = pts4[widx(base + 3)];

    unsigned a0 = ACC_INIT, a1 = ACC_INIT, a2 = ACC_INIT, a3 = ACC_INIT;

#define PAIR(A, XG, YG, QG, W)                                                 \
    {                                                                          \
        const float e  = __fadd_rn(__fmul_rn((W).x, XG), __fmul_rn((W).y, YG));\
        const float t  = __fadd_rn(QG, (W).z);                                 \
        const float d2 = __fadd_rn(t, e);                                      \
        const unsigned c = __float_as_uint(d2) - 1u;                           \
        A = (c < A) ? c : A;                                                   \
    }
#define STEP(K)                                                                \
    {                                                                          \
        float4 wn = pts4[widx(base + (K) + 4)];                                \
        PAIR(a0, xo0, yo0, qo0, w0)                                            \
        PAIR(a1, xo1, yo1, qo1, w1)                                            \
        PAIR(a2, xo2, yo2, qo2, w2)                                            \
        PAIR(a3, xo3, yo3, qo3, w3)                                            \
        w0 = w1; w1 = w2; w2 = w3; w3 = wn;                                    \
    }

    if (q != BPB - 1) {
        #pragma unroll
        for (int k = 0; k < KRANGE; ++k) STEP(k)
    } else {
        #pragma unroll
        for (int k = 0; k < KRANGE - 1; ++k) STEP(k)
        // k = 512: only pairs with n < 512 (thread-uniform: n0+3 <= 511)
        if (tid < 128) {
            PAIR(a0, xo0, yo0, qo0, w0)
            PAIR(a1, xo1, yo1, qo1, w1)
            PAIR(a2, xo2, yo2, qo2, w2)
            PAIR(a3, xo3, yo3, qo3, w3)
        }
    }
#undef STEP
#undef PAIR

    // ---- reduce: uint min across lanes, waves, block ----
    unsigned am = a0 < a1 ? a0 : a1;
    unsigned bm2 = a2 < a3 ? a2 : a3;
    am = am < bm2 ? am : bm2;
    #pragma unroll
    for (int off = 32; off >= 1; off >>= 1) {
        unsigned o = (unsigned)__shfl_xor((int)am, off, 64);
        am = o < am ? o : am;
    }
    if ((tid & 63) == 0) wm[tid >> 6] = am;
    __syncthreads();

    if (tid == 0) {
        unsigned m01 = wm[0] < wm[1] ? wm[0] : wm[1];
        unsigned m23 = wm[2] < wm[3] ? wm[2] : wm[3];
        unsigned bmn = m01 < m23 ? m01 : m23;
        atomicMin(ws, bmn);
        __threadfence();
        unsigned old = atomicAdd(ws + 1, 1u);   // init 0xFFFFFFFF: last sees NBLOCKS-2
        is_last = (old == (unsigned)(NBLOCKS - 2)) ? 1 : 0;
    }
    __syncthreads();

    if (is_last && tid == 0) {
        __threadfence();
        unsigned mbits = atomicMin(ws, 0xFFFFFFFFu);          // atomic read
        float minv = __uint_as_float(mbits + 1u);
        float ysum = __uint_as_float(atomicOr(ws + 2, 0u));   // atomic read
        float sr   = 1.0f - ysum * (1.0f / 64.0f);
        out[0] = sr + 5e-5f / sqrtf(minv);
    }
}

extern "C" void kernel_launch(void* const* d_in, const int* in_sizes, int n_in,
                              void* d_out, int out_size, void* d_ws, size_t ws_size,
                              hipStream_t stream) {
    const float* x = (const float*)d_in[0];   // (64, 20480) f32
    const float* Y = (const float*)d_in[1];   // (64, 1)     f32
    float* out = (float*)d_out;               // scalar f32
    unsigned* ws = (unsigned*)d_ws;

    // ws[0] = 0xFFFFFFFF (min init), ws[1] = 0xFFFFFFFF (counter init)
    hipMemsetAsync(d_ws, 0xFF, 8, stream);
    spike_kernel<<<dim3(NBLOCKS), dim3(256), 0, stream>>>(x, Y, out, ws);
}

// Round 5
// 69.674 us; speedup vs baseline: 1.2754x; 1.2754x over previous
//
#include <hip/hip_runtime.h>
#include <math.h>

// out[0] = (1 - mean(Y)) + 5e-5 / sqrt(min_d2), min over 64 batches x all
// unordered pairs of 1024 2-D points (x[b,20k], x[b,20k+1]).
//
// Bit-exactness (verified absmax 0.0 in R1/R3/R4): reference
//   d2 = rn(rn(sq_n+sq_m) - 2*rn(rn(xx')+rn(yy'))).
// We store u=-2x, v=-2y (exact pow2 scalings commute with rounding), so
//   e = rn(u_m*x_n + v_m*y_n) = -2*rn(xx'+yy'),  d2 = rn(t + e)  bit-identical.
//
// Guard "d2 > 0" via uint-min: for d2>0 float bits order as uints;
// c = bits(d2)-1 maps +0 -> 0xFFFFFFFF, negatives -> >= 0x7FFFFFFF, both
// above any positive candidate and above ACC_INIT = bits(+INF)-1.
//
// Enumeration: circulant m=(n+k)&1023, k=1..511 all n, k=512 only n<512.
// 4 consecutive points per thread; float4 LDS window slides 1/step.
// Layout pts4[(j&3)*ROWLEN + (j>>2)] with duplicated 130-entry tail so no
// wrap; row of (base+c) is fixed for steps K = c (mod 4) and col increments
// by 1 per 4 steps -> 4 hoisted base pointers, window loads are
// ds_read_b128 with immediate offsets (zero per-step address VALU).
//
// R4 lesson: fused last-block finish (1024 blocks hammering one cacheline
// with device atomics + fenced readback) cost ~20us; separate 1-block
// finalize kernel with plain distinct-address stores is cheaper.

#define NPTS    1024
#define XCOLS   20480
#define PSTRIDE 20
#define BPB     16              // blocks per batch
#define KRANGE  32              // 512 / BPB k-shifts per block
#define NBLOCKS (64 * BPB)      // 1024
#define ROWLEN  386             // 256 cols + 130 duplicated tail
#define ACC_INIT 0x7F7FFFFFu    // bits(+INF) - 1

__global__ __launch_bounds__(256) void pair_min_kernel(const float* __restrict__ x,
                                                       float* __restrict__ block_min) {
    __shared__ float4 pts4[4 * ROWLEN];
    __shared__ unsigned wm[4];

    const int b   = blockIdx.x >> 4;        // batch
    const int q   = blockIdx.x & (BPB - 1); // k-slice
    const int tid = threadIdx.x;

    // ---- stage batch points into LDS as (u=-2x, v=-2y, sq, 0) ----
    const float* xb = x + (size_t)b * XCOLS;
    #pragma unroll
    for (int i0 = 0; i0 < NPTS; i0 += 256) {
        const int i = i0 + tid;
        float2 p = *reinterpret_cast<const float2*>(xb + i * PSTRIDE);
        float sq = __fadd_rn(__fmul_rn(p.x, p.x), __fmul_rn(p.y, p.y));
        float4 v = make_float4(__fmul_rn(-2.0f, p.x), __fmul_rn(-2.0f, p.y), sq, 0.0f);
        const int g = i & 3, r = i >> 2;
        pts4[g * ROWLEN + r] = v;
        if (r < 130) pts4[g * ROWLEN + 256 + r] = v;   // wrap duplicate
    }
    __syncthreads();

    // ---- own 4 points (x = -0.5*u exact) ----
    float xo0, yo0, qo0, xo1, yo1, qo1, xo2, yo2, qo2, xo3, yo3, qo3;
    {
        float4 t;
        t = pts4[0 * ROWLEN + tid]; xo0 = __fmul_rn(-0.5f, t.x); yo0 = __fmul_rn(-0.5f, t.y); qo0 = t.z;
        t = pts4[1 * ROWLEN + tid]; xo1 = __fmul_rn(-0.5f, t.x); yo1 = __fmul_rn(-0.5f, t.y); qo1 = t.z;
        t = pts4[2 * ROWLEN + tid]; xo2 = __fmul_rn(-0.5f, t.x); yo2 = __fmul_rn(-0.5f, t.y); qo2 = t.z;
        t = pts4[3 * ROWLEN + tid]; xo3 = __fmul_rn(-0.5f, t.x); yo3 = __fmul_rn(-0.5f, t.y); qo3 = t.z;
    }

    const int n0     = tid << 2;
    const int kstart = q * KRANGE + 1;
    const int base   = n0 + kstart;

    // 4 hoisted window base pointers: p[c] points at element (base+c);
    // element (base+c+4t) lives at p[c] + t (same row, col+t).
    const float4* p0 = &pts4[((base    ) & 3) * ROWLEN + ((base    ) >> 2)];
    const float4* p1 = &pts4[((base + 1) & 3) * ROWLEN + ((base + 1) >> 2)];
    const float4* p2 = &pts4[((base + 2) & 3) * ROWLEN + ((base + 2) >> 2)];
    const float4* p3 = &pts4[((base + 3) & 3) * ROWLEN + ((base + 3) >> 2)];

    float4 w0 = p0[0], w1 = p1[0], w2 = p2[0], w3 = p3[0];

    unsigned a0 = ACC_INIT, a1 = ACC_INIT, a2 = ACC_INIT, a3 = ACC_INIT;

#define PAIR(A, XG, YG, QG, W)                                                 \
    {                                                                          \
        const float e  = __fadd_rn(__fmul_rn((W).x, XG), __fmul_rn((W).y, YG));\
        const float t  = __fadd_rn(QG, (W).z);                                 \
        const float d2 = __fadd_rn(t, e);                                      \
        const unsigned c = __float_as_uint(d2) - 1u;                           \
        A = (c < A) ? c : A;                                                   \
    }
    // window element for step K (reads point base+K+4): p[K&3][(K>>2)+1]
#define STEP(K)                                                                \
    {                                                                          \
        const float4 wn = ((K & 3) == 0 ? p0 : (K & 3) == 1 ? p1               \
                         : (K & 3) == 2 ? p2 : p3)[(K >> 2) + 1];              \
        PAIR(a0, xo0, yo0, qo0, w0)                                            \
        PAIR(a1, xo1, yo1, qo1, w1)                                            \
        PAIR(a2, xo2, yo2, qo2, w2)                                            \
        PAIR(a3, xo3, yo3, qo3, w3)                                            \
        w0 = w1; w1 = w2; w2 = w3; w3 = wn;                                    \
    }

    if (q != BPB - 1) {
        #pragma unroll
        for (int k = 0; k < KRANGE; ++k) STEP(k)
    } else {
        #pragma unroll
        for (int k = 0; k < KRANGE - 1; ++k) STEP(k)
        // k = 512: only pairs with n < 512 (thread-uniform: n0+3 <= 511)
        if (tid < 128) {
            PAIR(a0, xo0, yo0, qo0, w0)
            PAIR(a1, xo1, yo1, qo1, w1)
            PAIR(a2, xo2, yo2, qo2, w2)
            PAIR(a3, xo3, yo3, qo3, w3)
        }
    }
#undef STEP
#undef PAIR

    // ---- block-level uint-min reduce, plain store to distinct address ----
    unsigned am  = a0 < a1 ? a0 : a1;
    unsigned bm2 = a2 < a3 ? a2 : a3;
    am = am < bm2 ? am : bm2;
    #pragma unroll
    for (int off = 32; off >= 1; off >>= 1) {
        unsigned o = (unsigned)__shfl_xor((int)am, off, 64);
        am = o < am ? o : am;
    }
    if ((tid & 63) == 0) wm[tid >> 6] = am;
    __syncthreads();
    if (tid == 0) {
        unsigned m01 = wm[0] < wm[1] ? wm[0] : wm[1];
        unsigned m23 = wm[2] < wm[3] ? wm[2] : wm[3];
        unsigned bmn = m01 < m23 ? m01 : m23;
        block_min[blockIdx.x] = __uint_as_float(bmn + 1u);  // back to float d2
    }
}

__global__ __launch_bounds__(256) void finalize_kernel(const float* __restrict__ block_min,
                                                       const float* __restrict__ Y,
                                                       float* __restrict__ out) {
    const int tid = threadIdx.x;

    float v = block_min[tid];
    v = fminf(v, block_min[tid + 256]);
    v = fminf(v, block_min[tid + 512]);
    v = fminf(v, block_min[tid + 768]);
    #pragma unroll
    for (int off = 32; off >= 1; off >>= 1)
        v = fminf(v, __shfl_xor(v, off, 64));

    __shared__ float wmins[4];
    __shared__ float ysum_s;
    if ((tid & 63) == 0) wmins[tid >> 6] = v;

    float ys = (tid < 64) ? Y[tid] : 0.0f;
    #pragma unroll
    for (int off = 32; off >= 1; off >>= 1)
        ys += __shfl_xor(ys, off, 64);
    if (tid == 0) ysum_s = ys;
    __syncthreads();

    if (tid == 0) {
        const float minv = fminf(fminf(wmins[0], wmins[1]),
                                 fminf(wmins[2], wmins[3]));
        const float sr   = 1.0f - ysum_s * (1.0f / 64.0f);
        out[0] = sr + 5e-5f / __fsqrt_rn(minv);
    }
}

extern "C" void kernel_launch(void* const* d_in, const int* in_sizes, int n_in,
                              void* d_out, int out_size, void* d_ws, size_t ws_size,
                              hipStream_t stream) {
    const float* x = (const float*)d_in[0];   // (64, 20480) f32
    const float* Y = (const float*)d_in[1];   // (64, 1)     f32
    float* out  = (float*)d_out;              // scalar f32
    float* bmin = (float*)d_ws;               // 1024 floats of scratch

    pair_min_kernel<<<dim3(NBLOCKS), dim3(256), 0, stream>>>(x, bmin);
    finalize_kernel<<<dim3(1), dim3(256), 0, stream>>>(bmin, Y, out);
}

// Round 6
// 68.384 us; speedup vs baseline: 1.2994x; 1.0189x over previous
//
#include <hip/hip_runtime.h>
#include <math.h>

// out[0] = (1 - mean(Y)) + 5e-5 / sqrt(min_d2), min over 64 batches x all
// unordered pairs of 1024 2-D points (x[b,20k], x[b,20k+1]).
//
// Bit-exactness (verified absmax 0.0 in R1/R3/R4/R5): reference
//   d2 = rn(rn(sq_n+sq_m) - 2*rn(rn(xx')+rn(yy'))).
// We store u=-2x, v=-2y (exact pow2 scalings commute with rounding), so
//   e = rn(u_m*x_n + v_m*y_n) = -2*rn(xx'+yy'),  d2 = rn(t + e) bit-identical.
// No FMA anywhere in the d2 chain (__f*_rn barriers).
//
// Guard "d2 > 0" via uint-min: for d2>0 float bits order as uints;
// c = bits(d2)-1 maps +0 -> 0xFFFFFFFF, negatives -> >= 0x7FFFFFFF, both
// above any positive candidate and above ACC_INIT = bits(+INF)-1.
//
// Enumeration: circulant m=(n+k)&1023, k=1..511 all n, k=512 only n<512.
// Thread owns 4 consecutive points; partner of own-point c at step K is
// element base+K+c (base = 4*tid + kstart).
//
// R6 restructure: process steps in GROUPS of 4 (16 pairs/group) over a
// 7-element register window E0..E6 = points base+4t .. base+4t+6; the next
// group's 4 independent ds_read_b128 are issued BEFORE the current group's
// 112 VALU ops -> LDS latency hidden by ILP (R5's 1-step prefetch left only
// ~42cy of cover vs ~120cy latency; that was the measured 3x-above-floor).
// Layout pts4[(j&3)*ROWLEN + (j>>2)], rows padded with 130 duplicated tail
// entries so indices up to base+38 never wrap; element base+c+4t = p_c[t]
// (immediate-offset b128 loads off 4 hoisted pointers).
//
// R4 lesson kept: separate 1-block finalize kernel; no device atomics.

#define NPTS    1024
#define XCOLS   20480
#define PSTRIDE 20
#define BPB     16              // blocks per batch
#define KRANGE  32              // 512 / BPB k-shifts per block
#define NBLOCKS (64 * BPB)      // 1024
#define ROWLEN  386             // 256 cols + 130 duplicated tail
#define ACC_INIT 0x7F7FFFFFu    // bits(+INF) - 1

__global__ __launch_bounds__(256) void pair_min_kernel(const float* __restrict__ x,
                                                       float* __restrict__ block_min) {
    __shared__ float4 pts4[4 * ROWLEN];
    __shared__ unsigned wm[4];

    const int b   = blockIdx.x >> 4;        // batch
    const int q   = blockIdx.x & (BPB - 1); // k-slice
    const int tid = threadIdx.x;

    // ---- stage batch points into LDS as (u=-2x, v=-2y, sq, 0) ----
    const float* xb = x + (size_t)b * XCOLS;
    #pragma unroll
    for (int i0 = 0; i0 < NPTS; i0 += 256) {
        const int i = i0 + tid;
        float2 p = *reinterpret_cast<const float2*>(xb + i * PSTRIDE);
        float sq = __fadd_rn(__fmul_rn(p.x, p.x), __fmul_rn(p.y, p.y));
        float4 v = make_float4(__fmul_rn(-2.0f, p.x), __fmul_rn(-2.0f, p.y), sq, 0.0f);
        const int g = i & 3, r = i >> 2;
        pts4[g * ROWLEN + r] = v;
        if (r < 130) pts4[g * ROWLEN + 256 + r] = v;   // wrap duplicate
    }
    __syncthreads();

    // ---- own 4 points (x = -0.5*u exact) ----
    float xo0, yo0, qo0, xo1, yo1, qo1, xo2, yo2, qo2, xo3, yo3, qo3;
    {
        float4 t;
        t = pts4[0 * ROWLEN + tid]; xo0 = __fmul_rn(-0.5f, t.x); yo0 = __fmul_rn(-0.5f, t.y); qo0 = t.z;
        t = pts4[1 * ROWLEN + tid]; xo1 = __fmul_rn(-0.5f, t.x); yo1 = __fmul_rn(-0.5f, t.y); qo1 = t.z;
        t = pts4[2 * ROWLEN + tid]; xo2 = __fmul_rn(-0.5f, t.x); yo2 = __fmul_rn(-0.5f, t.y); qo2 = t.z;
        t = pts4[3 * ROWLEN + tid]; xo3 = __fmul_rn(-0.5f, t.x); yo3 = __fmul_rn(-0.5f, t.y); qo3 = t.z;
    }

    const int n0     = tid << 2;
    const int kstart = q * KRANGE + 1;
    const int base   = n0 + kstart;

    // element base+c+4t lives at p_c[t] (row (base+c)&3 fixed, col +t)
    const float4* p0 = &pts4[((base    ) & 3) * ROWLEN + ((base    ) >> 2)];
    const float4* p1 = &pts4[((base + 1) & 3) * ROWLEN + ((base + 1) >> 2)];
    const float4* p2 = &pts4[((base + 2) & 3) * ROWLEN + ((base + 2) >> 2)];
    const float4* p3 = &pts4[((base + 3) & 3) * ROWLEN + ((base + 3) >> 2)];

    unsigned a0 = ACC_INIT, a1 = ACC_INIT, a2 = ACC_INIT, a3 = ACC_INIT;

#define PAIR(A, XG, YG, QG, W)                                                 \
    {                                                                          \
        const float e  = __fadd_rn(__fmul_rn((W).x, XG), __fmul_rn((W).y, YG));\
        const float t  = __fadd_rn(QG, (W).z);                                 \
        const float d2 = __fadd_rn(t, e);                                      \
        const unsigned c = __float_as_uint(d2) - 1u;                           \
        A = (c < A) ? c : A;                                                   \
    }
    // one step: own-point c pairs with window element E_{K'+c}
#define STEP4(EA, EB, EC, ED)                                                  \
    PAIR(a0, xo0, yo0, qo0, EA)                                                \
    PAIR(a1, xo1, yo1, qo1, EB)                                                \
    PAIR(a2, xo2, yo2, qo2, EC)                                                \
    PAIR(a3, xo3, yo3, qo3, ED)

    // prologue: window for group 0 = elements base+0 .. base+6
    float4 E0 = p0[0], E1 = p1[0], E2 = p2[0], E3 = p3[0];
    float4 E4 = p0[1], E5 = p1[1], E6 = p2[1];

    #pragma unroll
    for (int t = 0; t < 7; ++t) {
        // prefetch next group's new elements: base+4t+7 .. base+4t+10
        const float4 N3 = p3[t + 1];
        const float4 N4 = p0[t + 2];
        const float4 N5 = p1[t + 2];
        const float4 N6 = p2[t + 2];
        // steps 4t .. 4t+3 (16 pairs), window E0..E6 = base+4t .. base+4t+6
        STEP4(E0, E1, E2, E3)
        STEP4(E1, E2, E3, E4)
        STEP4(E2, E3, E4, E5)
        STEP4(E3, E4, E5, E6)
        // slide by 4
        E0 = E4; E1 = E5; E2 = E6;
        E3 = N3; E4 = N4; E5 = N5; E6 = N6;
    }

    // epilogue: steps 28..31, window E0..E6 = base+28 .. base+34 (no loads)
    STEP4(E0, E1, E2, E3)
    STEP4(E1, E2, E3, E4)
    STEP4(E2, E3, E4, E5)
    // step 31 is k = kstart+31; equals 512 only for q == BPB-1, where only
    // pairs with n < 512 count (thread-uniform: n0+3 <= 511 <=> tid < 128)
    if (q != BPB - 1 || tid < 128) {
        STEP4(E3, E4, E5, E6)
    }
#undef STEP4
#undef PAIR

    // ---- block-level uint-min reduce, plain store to distinct address ----
    unsigned am  = a0 < a1 ? a0 : a1;
    unsigned bm2 = a2 < a3 ? a2 : a3;
    am = am < bm2 ? am : bm2;
    #pragma unroll
    for (int off = 32; off >= 1; off >>= 1) {
        unsigned o = (unsigned)__shfl_xor((int)am, off, 64);
        am = o < am ? o : am;
    }
    if ((tid & 63) == 0) wm[tid >> 6] = am;
    __syncthreads();
    if (tid == 0) {
        unsigned m01 = wm[0] < wm[1] ? wm[0] : wm[1];
        unsigned m23 = wm[2] < wm[3] ? wm[2] : wm[3];
        unsigned bmn = m01 < m23 ? m01 : m23;
        block_min[blockIdx.x] = __uint_as_float(bmn + 1u);  // back to float d2
    }
}

__global__ __launch_bounds__(256) void finalize_kernel(const float* __restrict__ block_min,
                                                       const float* __restrict__ Y,
                                                       float* __restrict__ out) {
    const int tid = threadIdx.x;

    float v = block_min[tid];
    v = fminf(v, block_min[tid + 256]);
    v = fminf(v, block_min[tid + 512]);
    v = fminf(v, block_min[tid + 768]);
    #pragma unroll
    for (int off = 32; off >= 1; off >>= 1)
        v = fminf(v, __shfl_xor(v, off, 64));

    __shared__ float wmins[4];
    __shared__ float ysum_s;
    if ((tid & 63) == 0) wmins[tid >> 6] = v;

    float ys = (tid < 64) ? Y[tid] : 0.0f;
    #pragma unroll
    for (int off = 32; off >= 1; off >>= 1)
        ys += __shfl_xor(ys, off, 64);
    if (tid == 0) ysum_s = ys;
    __syncthreads();

    if (tid == 0) {
        const float minv = fminf(fminf(wmins[0], wmins[1]),
                                 fminf(wmins[2], wmins[3]));
        const float sr   = 1.0f - ysum_s * (1.0f / 64.0f);
        out[0] = sr + 5e-5f / __fsqrt_rn(minv);
    }
}

extern "C" void kernel_launch(void* const* d_in, const int* in_sizes, int n_in,
                              void* d_out, int out_size, void* d_ws, size_t ws_size,
                              hipStream_t stream) {
    const float* x = (const float*)d_in[0];   // (64, 20480) f32
    const float* Y = (const float*)d_in[1];   // (64, 1)     f32
    float* out  = (float*)d_out;              // scalar f32
    float* bmin = (float*)d_ws;               // 1024 floats of scratch

    pair_min_kernel<<<dim3(NBLOCKS), dim3(256), 0, stream>>>(x, bmin);
    finalize_kernel<<<dim3(1), dim3(256), 0, stream>>>(bmin, Y, out);
}